// Round 1
// baseline (5499.395 us; speedup 1.0000x reference)
//
#include <hip/hip_runtime.h>
#include <math.h>
#include <stdint.h>

#define BBOX_CLAMP 4.135166556742356f
#define SQH 0.70710678118654752f
#define SQ2 1.41421356237309515f

__device__ __forceinline__ unsigned okey(float f){
  unsigned u = __float_as_uint(f);
  return (u & 0x80000000u) ? ~u : (u | 0x80000000u);
}

// ---------------- one-time weight transpose: wT[(cin*9+k)*256 + co] ----------------
__global__ void k_wtrans(const float* __restrict__ w, float* __restrict__ wT){
  const int ck = blockIdx.x;      // cin*9+k  (0..2303)
  const int co = threadIdx.x;     // 0..255
  wT[ck*256 + co] = w[co*2304 + ck];
}

// ---------------- fused stem conv3x3+bias+relu + obj/box 1x1 heads ----------------
__global__ __launch_bounds__(256) void k_stem(
    const float* __restrict__ feat,   // [8][256][H][W]
    const float* __restrict__ wT,     // [2304][256]
    const float* __restrict__ bstem,  // [256]
    const float* __restrict__ wobj,   // [3][256]
    const float* __restrict__ bobj,   // [3]
    const float* __restrict__ wbox,   // [12][256]
    const float* __restrict__ bbox,   // [12]
    float* __restrict__ scores,       // [8][H*W*3]
    float* __restrict__ deltas,       // [8][H*W*12]
    const int H, const int W)
{
  __shared__ __align__(16) float in_t[10][12];
  __shared__ float x_lds[32][257];

  const int tx0 = blockIdx.x*8, ty0 = blockIdx.y*8;
  const int b = blockIdx.z;
  const int co = threadIdx.x;
  const size_t HW = (size_t)H*W;
  const float* fb = feat + (size_t)b*256*HW;

  float acc[64];
#pragma unroll
  for (int i=0;i<64;++i) acc[i]=0.f;

  for (int cin=0; cin<256; ++cin){
    __syncthreads();                      // protect in_t from prior iteration readers
    if (co < 100){
      const int ty = co/10, tx = co%10;
      const int gy = ty0-1+ty, gx = tx0-1+tx;
      float v = 0.f;
      if (gy>=0 && gy<H && gx>=0 && gx<W) v = fb[cin*HW + (size_t)gy*W + gx];
      in_t[ty][tx] = v;
    }
    float wr[9];
#pragma unroll
    for (int k=0;k<9;++k) wr[k] = wT[(cin*9+k)*256 + co];
    __syncthreads();

    float r[3][12];
#define LOADROW(s_, row_) { \
    const float4 a0 = *reinterpret_cast<const float4*>(&in_t[row_][0]); \
    const float4 a1 = *reinterpret_cast<const float4*>(&in_t[row_][4]); \
    const float4 a2 = *reinterpret_cast<const float4*>(&in_t[row_][8]); \
    r[s_][0]=a0.x; r[s_][1]=a0.y; r[s_][2]=a0.z; r[s_][3]=a0.w; \
    r[s_][4]=a1.x; r[s_][5]=a1.y; r[s_][6]=a1.z; r[s_][7]=a1.w; \
    r[s_][8]=a2.x; r[s_][9]=a2.y; r[s_][10]=a2.z; r[s_][11]=a2.w; }

    LOADROW(0,0)
    LOADROW(1,1)
    LOADROW(2,2)
#pragma unroll
    for (int py=0; py<8; ++py){
      if (py >= 1){ LOADROW((py+2)%3, (py+2)) }
#pragma unroll
      for (int px=0; px<8; ++px){
        float s = acc[py*8+px];
#pragma unroll
        for (int kh=0; kh<3; ++kh){
          const int rs = (py+kh)%3;
          s = fmaf(r[rs][px+0], wr[kh*3+0], s);
          s = fmaf(r[rs][px+1], wr[kh*3+1], s);
          s = fmaf(r[rs][px+2], wr[kh*3+2], s);
        }
        acc[py*8+px] = s;
      }
    }
#undef LOADROW
  }

  // bias + relu
  const float bs = bstem[co];
#pragma unroll
  for (int i=0;i<64;++i) acc[i] = fmaxf(acc[i]+bs, 0.f);

  // heads: two halves of 32 pixels through LDS
  const int p_loc = co & 31;
  const int g = co >> 5;                 // 0..7
  const int oc0 = g*2, oc1 = g*2+1;      // oc in [0,16), 15 unused
  const float* wh0 = (oc0<3) ? (wobj + oc0*256) : (wbox + (oc0-3)*256);
  const float* wh1 = (oc1<3) ? (wobj + oc1*256) : ((oc1<15) ? (wbox + (oc1-3)*256) : wbox);
  const float bias0 = (oc0<3) ? bobj[oc0] : bbox[oc0-3];
  const float bias1 = (oc1<3) ? bobj[oc1] : ((oc1<15) ? bbox[oc1-3] : 0.f);

  for (int half=0; half<2; ++half){
    __syncthreads();
#pragma unroll
    for (int i=0;i<32;++i) x_lds[i][co] = acc[half*32 + i];
    __syncthreads();
    const int p  = half*32 + p_loc;
    const int py = p>>3, px = p&7;
    const int hh = ty0+py, ww = tx0+px;
    const size_t loc = (size_t)hh*W + ww;
    float s0 = 0.f, s1 = 0.f;
#pragma unroll 8
    for (int c=0;c<256;++c){
      const float xv = x_lds[p_loc][c];
      s0 = fmaf(xv, wh0[c], s0);
      s1 = fmaf(xv, wh1[c], s1);
    }
    s0 += bias0; s1 += bias1;
    if (oc0 < 3) scores[b*HW*3 + loc*3 + oc0] = s0;
    else         deltas[b*HW*12 + loc*12 + (oc0-3)] = s0;
    if (oc1 < 3) scores[b*HW*3 + loc*3 + oc1] = s1;
    else if (oc1 < 15) deltas[b*HW*12 + loc*12 + (oc1-3)] = s1;
  }
}

// ---------------- per (level,image): top-400 -> decode -> NMS -> top-50 ----------------
__global__ __launch_bounds__(1024) void k_select(
    float* __restrict__ sc3, float* __restrict__ sc4, float* __restrict__ sc5,
    const float* __restrict__ dl3, const float* __restrict__ dl4, const float* __restrict__ dl5,
    float* __restrict__ out)
{
  const int lvl = blockIdx.x >> 3;
  const int b   = blockIdx.x & 7;
  int N, W; float stride; float* sc; const float* dl;
  if (lvl==0){ N=49152; W=128; stride=8.f;  sc=sc3; dl=dl3; }
  else if (lvl==1){ N=12288; W=64; stride=16.f; sc=sc4; dl=dl4; }
  else { N=3072; W=32; stride=32.f; sc=sc5; dl=dl5; }
  sc += (size_t)b*N;
  dl += (size_t)b*(size_t)(N/3)*12;

  __shared__ unsigned wkey[16];
  __shared__ int widx[16];
  __shared__ int sli;
  __shared__ int tk[400];
  __shared__ float bx1[400], by1[400], bx2[400], by2[400], bar_[400];
  __shared__ int keep[400];
  __shared__ int olist[50];

  const int t = threadIdx.x;
  const int chunk = N >> 10;       // N/1024: 48 / 12 / 3
  const int base = t*chunk;

  // per-thread cached local max over its contiguous chunk
  unsigned lkey = 0u; int lidx = 0;
  for (int j=0;j<chunk;++j){
    const unsigned u = okey(sc[base+j]);
    if (u > lkey){ lkey=u; lidx=base+j; }
  }

  for (int sel=0; sel<400; ++sel){
    unsigned k = lkey; int ii = lidx;
#pragma unroll
    for (int off=32; off>0; off>>=1){
      const unsigned k2 = __shfl_xor(k, off, 64);
      const int      i2 = __shfl_xor(ii, off, 64);
      if (k2 > k || (k2==k && i2 < ii)){ k=k2; ii=i2; }
    }
    if ((t & 63)==0){ wkey[t>>6]=k; widx[t>>6]=ii; }
    __syncthreads();
    if (t==0){
      unsigned bk = wkey[0]; int bi = widx[0];
      for (int wv=1; wv<16; ++wv){
        if (wkey[wv] > bk || (wkey[wv]==bk && widx[wv] < bi)){ bk=wkey[wv]; bi=widx[wv]; }
      }
      sli = bi; tk[sel] = bi;
    }
    __syncthreads();
    const int win = sli;
    if (win >= base && win < base+chunk){
      sc[win] = -INFINITY;           // mark taken; rewritten fresh by k_stem every launch
      lkey = 0u; lidx = 0;
      for (int j=0;j<chunk;++j){
        const unsigned u = okey(sc[base+j]);
        if (u > lkey){ lkey=u; lidx=base+j; }
      }
    }
  }
  __syncthreads();

  // decode 400 boxes
  if (t < 400){
    const int gi = tk[t];
    const int loc = gi/3, a = gi - loc*3;
    const int hh = loc / W, ww = loc - hh*W;
    const float cx = (ww + 0.5f)*stride, cy = (hh + 0.5f)*stride;
    const float size = stride*8.f;
    const float sq = (a==0) ? SQH : ((a==1) ? 1.f : SQ2);
    const float hw_ = 0.5f*(size/sq);    // half width  (w = size/sqrt(r))
    const float hv_ = 0.5f*(size*sq);    // half height (h = size*sqrt(r))
    const float ax1 = cx - hw_, ax2 = cx + hw_;
    const float ay1 = cy - hv_, ay2 = cy + hv_;
    const float aw = ax2 - ax1, ah = ay2 - ay1;
    const float acx = ax1 + 0.5f*aw, acy = ay1 + 0.5f*ah;
    const float* dd = dl + (size_t)loc*12 + a*4;
    const float dx = dd[0], dy = dd[1];
    const float dw = fminf(fmaxf(dd[2], -BBOX_CLAMP), BBOX_CLAMP);
    const float dh = fminf(fmaxf(dd[3], -BBOX_CLAMP), BBOX_CLAMP);
    const float pcx = acx + dx*aw;
    const float pcy = acy + dy*ah;
    const float pw = aw*expf(dw);
    const float ph = ah*expf(dh);
    const float x1 = pcx - 0.5f*pw, y1 = pcy - 0.5f*ph;
    const float x2 = pcx + 0.5f*pw, y2 = pcy + 0.5f*ph;
    bx1[t]=x1; by1[t]=y1; bx2[t]=x2; by2[t]=y2;
    bar_[t] = fmaxf(x2-x1, 0.f)*fmaxf(y2-y1, 0.f);
    keep[t] = 1;
  }
  __syncthreads();

  // sequential NMS (i ascending = descending score), j parallel
  for (int i=0;i<399;++i){
    if (keep[i]){
      const float xi1=bx1[i], yi1=by1[i], xi2=bx2[i], yi2=by2[i], ai=bar_[i];
      for (int j=i+1+t; j<400; j+=1024){
        const float ix1 = fmaxf(xi1, bx1[j]);
        const float iy1 = fmaxf(yi1, by1[j]);
        const float ix2 = fminf(xi2, bx2[j]);
        const float iy2 = fminf(yi2, by2[j]);
        const float inter = fmaxf(ix2-ix1, 0.f)*fmaxf(iy2-iy1, 0.f);
        const float iou = inter / fmaxf(ai + bar_[j] - inter, 1e-8f);
        if (iou > 0.6f) keep[j] = 0;
      }
    }
    __syncthreads();
  }

  // top-50 of masked scores: kept (already score-descending) first, then -inf ties by index
  if (t==0){
    int cnt=0;
    for (int i=0;i<400 && cnt<50;++i) if (keep[i])  olist[cnt++]=i;
    for (int i=0;i<400 && cnt<50;++i) if (!keep[i]) olist[cnt++]=i;
  }
  __syncthreads();
  if (t < 50){
    const int j = olist[t];
    float* o = out + (size_t)b*600 + (size_t)(lvl*50 + t)*4;
    o[0]=bx1[j]; o[1]=by1[j]; o[2]=bx2[j]; o[3]=by2[j];
  }
}

extern "C" void kernel_launch(void* const* d_in, const int* in_sizes, int n_in,
                              void* d_out, int out_size, void* d_ws, size_t ws_size,
                              hipStream_t stream) {
  (void)in_sizes; (void)n_in; (void)out_size; (void)ws_size;
  const float* p3     = (const float*)d_in[0];
  const float* p4     = (const float*)d_in[1];
  const float* p5     = (const float*)d_in[2];
  const float* w_stem = (const float*)d_in[3];
  const float* b_stem = (const float*)d_in[4];
  const float* w_obj  = (const float*)d_in[5];
  const float* b_obj  = (const float*)d_in[6];
  const float* w_box  = (const float*)d_in[7];
  const float* b_box  = (const float*)d_in[8];
  float* out = (float*)d_out;

  float* ws  = (float*)d_ws;
  float* wT  = ws;                    // 2304*256          = 589824
  float* sc3 = wT  + 589824;          // 8*128*128*3       = 393216
  float* sc4 = sc3 + 393216;          // 8*64*64*3         =  98304
  float* sc5 = sc4 + 98304;           // 8*32*32*3         =  24576
  float* dl3 = sc5 + 24576;           // 8*128*128*12      = 1572864
  float* dl4 = dl3 + 1572864;         // 8*64*64*12        = 393216
  float* dl5 = dl4 + 393216;          // 8*32*32*12        =  98304

  k_wtrans<<<dim3(2304), dim3(256), 0, stream>>>(w_stem, wT);

  k_stem<<<dim3(16,16,8), dim3(256), 0, stream>>>(p3, wT, b_stem, w_obj, b_obj, w_box, b_box, sc3, dl3, 128, 128);
  k_stem<<<dim3(8,8,8),   dim3(256), 0, stream>>>(p4, wT, b_stem, w_obj, b_obj, w_box, b_box, sc4, dl4, 64, 64);
  k_stem<<<dim3(4,4,8),   dim3(256), 0, stream>>>(p5, wT, b_stem, w_obj, b_obj, w_box, b_box, sc5, dl5, 32, 32);

  k_select<<<dim3(24), dim3(1024), 0, stream>>>(sc3, sc4, sc5, dl3, dl4, dl5, out);
}

// Round 2
// 4461.515 us; speedup vs baseline: 1.2326x; 1.2326x over previous
//
#include <hip/hip_runtime.h>
#include <math.h>
#include <stdint.h>

#define BBOX_CLAMP 4.135166556742356f
#define SQH 0.70710678118654752f
#define SQ2 1.41421356237309515f

__device__ __forceinline__ unsigned okey(float f){
  unsigned u = __float_as_uint(f);
  return (u & 0x80000000u) ? ~u : (u | 0x80000000u);
}

// ---------------- one-time weight transpose: wT[(cin*9+k)*256 + co] ----------------
__global__ void k_wtrans(const float* __restrict__ w, float* __restrict__ wT){
  const int ck = blockIdx.x;      // cin*9+k  (0..2303)
  const int co = threadIdx.x;     // 0..255
  wT[ck*256 + co] = w[co*2304 + ck];
}

// ---------------- fused stem conv3x3+bias+relu + obj/box 1x1 heads ----------------
__global__ __launch_bounds__(256) void k_stem(
    const float* __restrict__ feat,   // [8][256][H][W]
    const float* __restrict__ wT,     // [2304][256]
    const float* __restrict__ bstem,  // [256]
    const float* __restrict__ wobj,   // [3][256]
    const float* __restrict__ bobj,   // [3]
    const float* __restrict__ wbox,   // [12][256]
    const float* __restrict__ bbox,   // [12]
    float* __restrict__ scores,       // [8][H*W*3]
    float* __restrict__ deltas,       // [8][H*W*12]
    const int H, const int W)
{
  __shared__ __align__(16) float in_t[2][2][10][12];  // [buf][sub][row][col]
  __shared__ float x_lds[32][257];

  const int tx0 = blockIdx.x*8, ty0 = blockIdx.y*8;
  const int b = blockIdx.z;
  const int co = threadIdx.x;
  const size_t HW = (size_t)H*W;
  const float* fb = feat + (size_t)b*256*HW;

  // loader thread mapping: threads 0..199 load two 10x10 tiles (sub 0/1)
  const int  lsub = co / 100;
  const int  lin  = co - lsub*100;
  const int  lty = lin/10, ltx = lin - (lin/10)*10;
  const int  gy = ty0-1+lty, gx = tx0-1+ltx;
  const bool lactive = (co < 200);
  const bool inb = lactive && (gy>=0 && gy<H && gx>=0 && gx<W);
  const size_t goff = inb ? ((size_t)gy*W + gx) : 0;

  float acc[64];
#pragma unroll
  for (int i=0;i<64;++i) acc[i]=0.f;

  // preload pair 0 into buf 0
  if (lactive){
    in_t[0][lsub][lty][ltx] = inb ? fb[(size_t)lsub*HW + goff] : 0.f;
  }
  // preload weights for pair 0
  float wcur[18], wnxt[18];
#pragma unroll
  for (int k=0;k<18;++k) wcur[k] = wT[k*256 + co];
  __syncthreads();

  for (int it=0; it<128; ++it){
    const int buf = it & 1;

    // issue next-pair loads early (register staging, T14)
    float pv = 0.f;
    if (it < 127){
      if (inb) pv = fb[(size_t)(2*(it+1)+lsub)*HW + goff];
#pragma unroll
      for (int k=0;k<18;++k) wnxt[k] = wT[((2*it+2)*9 + k)*256 + co];
    }

    float r[3][12];
#define LOADROW(s_, row_) { \
    const float4 a0 = *reinterpret_cast<const float4*>(&in_t[buf][sub][row_][0]); \
    const float4 a1 = *reinterpret_cast<const float4*>(&in_t[buf][sub][row_][4]); \
    const float4 a2 = *reinterpret_cast<const float4*>(&in_t[buf][sub][row_][8]); \
    r[s_][0]=a0.x; r[s_][1]=a0.y; r[s_][2]=a0.z; r[s_][3]=a0.w; \
    r[s_][4]=a1.x; r[s_][5]=a1.y; r[s_][6]=a1.z; r[s_][7]=a1.w; \
    r[s_][8]=a2.x; r[s_][9]=a2.y; r[s_][10]=a2.z; r[s_][11]=a2.w; }

#pragma unroll
    for (int sub=0; sub<2; ++sub){
      LOADROW(0,0)
      LOADROW(1,1)
      LOADROW(2,2)
#pragma unroll
      for (int py=0; py<8; ++py){
        if (py >= 1){ LOADROW((py+2)%3, (py+2)) }
#pragma unroll
        for (int px=0; px<8; ++px){
          float s = acc[py*8+px];
#pragma unroll
          for (int kh=0; kh<3; ++kh){
            const int rs = (py+kh)%3;
            s = fmaf(r[rs][px+0], wcur[sub*9+kh*3+0], s);
            s = fmaf(r[rs][px+1], wcur[sub*9+kh*3+1], s);
            s = fmaf(r[rs][px+2], wcur[sub*9+kh*3+2], s);
          }
          acc[py*8+px] = s;
        }
      }
    }
#undef LOADROW

    // late LDS write of the prefetched tile (after compute)
    if (it < 127){
      if (lactive) in_t[buf^1][lsub][lty][ltx] = pv;
#pragma unroll
      for (int k=0;k<18;++k) wcur[k] = wnxt[k];
    }
    __syncthreads();
  }

  // bias + relu
  const float bs = bstem[co];
#pragma unroll
  for (int i=0;i<64;++i) acc[i] = fmaxf(acc[i]+bs, 0.f);

  // heads: two halves of 32 pixels through LDS
  const int p_loc = co & 31;
  const int g = co >> 5;                 // 0..7
  const int oc0 = g*2, oc1 = g*2+1;      // oc in [0,16), 15 unused
  const float* wh0 = (oc0<3) ? (wobj + oc0*256) : (wbox + (oc0-3)*256);
  const float* wh1 = (oc1<3) ? (wobj + oc1*256) : ((oc1<15) ? (wbox + (oc1-3)*256) : wbox);
  const float bias0 = (oc0<3) ? bobj[oc0] : bbox[oc0-3];
  const float bias1 = (oc1<3) ? bobj[oc1] : ((oc1<15) ? bbox[oc1-3] : 0.f);

  for (int half=0; half<2; ++half){
    __syncthreads();
#pragma unroll
    for (int i=0;i<32;++i) x_lds[i][co] = acc[half*32 + i];
    __syncthreads();
    const int p  = half*32 + p_loc;
    const int py = p>>3, px = p&7;
    const int hh = ty0+py, ww = tx0+px;
    const size_t loc = (size_t)hh*W + ww;
    float s0 = 0.f, s1 = 0.f;
#pragma unroll 8
    for (int c=0;c<256;++c){
      const float xv = x_lds[p_loc][c];
      s0 = fmaf(xv, wh0[c], s0);
      s1 = fmaf(xv, wh1[c], s1);
    }
    s0 += bias0; s1 += bias1;
    if (oc0 < 3) scores[b*HW*3 + loc*3 + oc0] = s0;
    else         deltas[b*HW*12 + loc*12 + (oc0-3)] = s0;
    if (oc1 < 3) scores[b*HW*3 + loc*3 + oc1] = s1;
    else if (oc1 < 15) deltas[b*HW*12 + loc*12 + (oc1-3)] = s1;
  }
}

// ---------------- per (level,image): top-400 -> decode -> NMS -> top-50 ----------------
__global__ __launch_bounds__(1024) void k_select(
    const float* __restrict__ sc3, const float* __restrict__ sc4, const float* __restrict__ sc5,
    const float* __restrict__ dl3, const float* __restrict__ dl4, const float* __restrict__ dl5,
    float* __restrict__ out)
{
  const int lvl = blockIdx.x >> 3;
  const int b   = blockIdx.x & 7;
  int N, W; float stride; const float* sc; const float* dl;
  if (lvl==0){ N=49152; W=128; stride=8.f;  sc=sc3; dl=dl3; }
  else if (lvl==1){ N=12288; W=64; stride=16.f; sc=sc4; dl=dl4; }
  else { N=3072; W=32; stride=32.f; sc=sc5; dl=dl5; }
  sc += (size_t)b*N;
  dl += (size_t)b*(size_t)(N/3)*12;

  __shared__ unsigned hist[256];
  __shared__ unsigned s_prefix;
  __shared__ int s_need;
  __shared__ int s_cntc;
  __shared__ unsigned long long cand[1024];
  __shared__ int tk[400];
  __shared__ float bx1[400], by1[400], bx2[400], by2[400], bar_[400];
  __shared__ unsigned long long mask[400][7];
  __shared__ int olist[50];

  const int t = threadIdx.x;

  // ---- radix-select: find key K of the 400th-largest score ----
  if (t==0){ s_prefix=0u; s_need=400; }
  for (int pass=0; pass<4; ++pass){
    const int shift = 24 - 8*pass;
    if (t<256) hist[t]=0u;
    __syncthreads();
    const unsigned pref = s_prefix;
    for (int i=t; i<N; i+=1024){
      const unsigned k = okey(sc[i]);
      if (pass==0 || (k >> (shift+8)) == pref)
        atomicAdd(&hist[(k>>shift)&255u], 1u);
    }
    __syncthreads();
    if (t==0){
      int need = s_need, cum=0, bsel=0;
      for (int bb=255; bb>=0; --bb){
        const int h = (int)hist[bb];
        if (cum + h >= need){ bsel=bb; break; }
        cum += h;
      }
      s_prefix = (pref<<8) | (unsigned)bsel;
      s_need = need - cum;
    }
    __syncthreads();
  }
  const unsigned K = s_prefix;

  // ---- compact candidates: all keys >= K (count >= 400 by construction) ----
  if (t==0) s_cntc = 0;
  cand[t] = 0ull;
  __syncthreads();
  for (int i=t; i<N; i+=1024){
    const unsigned k = okey(sc[i]);
    if (k >= K){
      const int pos = atomicAdd(&s_cntc, 1);
      if (pos < 1024)
        cand[pos] = ((unsigned long long)k<<32) | (unsigned long long)(0xFFFFFFFFu - (unsigned)i);
    }
  }
  __syncthreads();

  // ---- bitonic sort 1024 descending: (key desc, idx asc) ----
  for (int kk=2; kk<=1024; kk<<=1){
    for (int j=kk>>1; j>0; j>>=1){
      const int ixj = t ^ j;
      if (ixj > t){
        const unsigned long long a = cand[t], c = cand[ixj];
        const bool descending = ((t & kk) == 0);
        if ((a < c) == descending){ cand[t]=c; cand[ixj]=a; }
      }
      __syncthreads();
    }
  }

  // ---- decode top-400 boxes ----
  if (t < 400){
    const unsigned long long c = cand[t];
    const int gi = (int)(0xFFFFFFFFu - (unsigned)(c & 0xFFFFFFFFull));
    tk[t] = gi;
    const int loc = gi/3, a = gi - loc*3;
    const int hh = loc / W, ww = loc - hh*W;
    const float cx = (ww + 0.5f)*stride, cy = (hh + 0.5f)*stride;
    const float size = stride*8.f;
    const float sq = (a==0) ? SQH : ((a==1) ? 1.f : SQ2);
    const float hw_ = 0.5f*(size/sq);    // half width  (w = size/sqrt(r))
    const float hv_ = 0.5f*(size*sq);    // half height (h = size*sqrt(r))
    const float ax1 = cx - hw_, ax2 = cx + hw_;
    const float ay1 = cy - hv_, ay2 = cy + hv_;
    const float aw = ax2 - ax1, ah = ay2 - ay1;
    const float acx = ax1 + 0.5f*aw, acy = ay1 + 0.5f*ah;
    const float* dd = dl + (size_t)loc*12 + a*4;
    const float dx = dd[0], dy = dd[1];
    const float dw = fminf(fmaxf(dd[2], -BBOX_CLAMP), BBOX_CLAMP);
    const float dh = fminf(fmaxf(dd[3], -BBOX_CLAMP), BBOX_CLAMP);
    const float pcx = acx + dx*aw;
    const float pcy = acy + dy*ah;
    const float pw = aw*expf(dw);
    const float ph = ah*expf(dh);
    const float x1 = pcx - 0.5f*pw, y1 = pcy - 0.5f*ph;
    const float x2 = pcx + 0.5f*pw, y2 = pcy + 0.5f*ph;
    bx1[t]=x1; by1[t]=y1; bx2[t]=x2; by2[t]=y2;
    bar_[t] = fmaxf(x2-x1, 0.f)*fmaxf(y2-y1, 0.f);
  }
  __syncthreads();

  // ---- parallel 400x400 suppression bitmask: mask[i][w] bits for j in [w*64, w*64+64), j>i ----
  for (int task=t; task<2800; task+=1024){
    const int i = task/7, w = task - (task/7)*7;
    unsigned long long m = 0ull;
    const float xi1=bx1[i], yi1=by1[i], xi2=bx2[i], yi2=by2[i], ai=bar_[i];
    const int j0 = w<<6;
    const int js = (j0 > i+1) ? j0 : (i+1);
    const int je = (j0+64 < 400) ? (j0+64) : 400;
    for (int j=js; j<je; ++j){
      const float ix1 = fmaxf(xi1, bx1[j]);
      const float iy1 = fmaxf(yi1, by1[j]);
      const float ix2 = fminf(xi2, bx2[j]);
      const float iy2 = fminf(yi2, by2[j]);
      const float inter = fmaxf(ix2-ix1, 0.f)*fmaxf(iy2-iy1, 0.f);
      const float iou = inter / fmaxf(ai + bar_[j] - inter, 1e-8f);
      if (iou > 0.6f) m |= (1ull << (j - j0));
    }
    mask[i][w] = m;
  }
  __syncthreads();

  // ---- serial suppression scan (single thread, word-parallel ANDs) + top-50 list ----
  if (t==0){
    unsigned long long keepw[7];
#pragma unroll
    for (int w=0;w<7;++w) keepw[w] = ~0ull;
    for (int i=0;i<400;++i){
      if ((keepw[i>>6] >> (i&63)) & 1ull){
#pragma unroll
        for (int w=0;w<7;++w) keepw[w] &= ~mask[i][w];
      }
    }
    int cnt=0;
    for (int i=0;i<400 && cnt<50;++i) if ( (keepw[i>>6]>>(i&63)) & 1ull) olist[cnt++]=i;
    for (int i=0;i<400 && cnt<50;++i) if (!((keepw[i>>6]>>(i&63)) & 1ull)) olist[cnt++]=i;
  }
  __syncthreads();

  if (t < 50){
    const int j = olist[t];
    float* o = out + (size_t)b*600 + (size_t)(lvl*50 + t)*4;
    o[0]=bx1[j]; o[1]=by1[j]; o[2]=bx2[j]; o[3]=by2[j];
  }
}

extern "C" void kernel_launch(void* const* d_in, const int* in_sizes, int n_in,
                              void* d_out, int out_size, void* d_ws, size_t ws_size,
                              hipStream_t stream) {
  (void)in_sizes; (void)n_in; (void)out_size; (void)ws_size;
  const float* p3     = (const float*)d_in[0];
  const float* p4     = (const float*)d_in[1];
  const float* p5     = (const float*)d_in[2];
  const float* w_stem = (const float*)d_in[3];
  const float* b_stem = (const float*)d_in[4];
  const float* w_obj  = (const float*)d_in[5];
  const float* b_obj  = (const float*)d_in[6];
  const float* w_box  = (const float*)d_in[7];
  const float* b_box  = (const float*)d_in[8];
  float* out = (float*)d_out;

  float* ws  = (float*)d_ws;
  float* wT  = ws;                    // 2304*256          = 589824
  float* sc3 = wT  + 589824;          // 8*128*128*3       = 393216
  float* sc4 = sc3 + 393216;          // 8*64*64*3         =  98304
  float* sc5 = sc4 + 98304;           // 8*32*32*3         =  24576
  float* dl3 = sc5 + 24576;           // 8*128*128*12      = 1572864
  float* dl4 = dl3 + 1572864;         // 8*64*64*12        = 393216
  float* dl5 = dl4 + 393216;          // 8*32*32*12        =  98304

  k_wtrans<<<dim3(2304), dim3(256), 0, stream>>>(w_stem, wT);

  k_stem<<<dim3(16,16,8), dim3(256), 0, stream>>>(p3, wT, b_stem, w_obj, b_obj, w_box, b_box, sc3, dl3, 128, 128);
  k_stem<<<dim3(8,8,8),   dim3(256), 0, stream>>>(p4, wT, b_stem, w_obj, b_obj, w_box, b_box, sc4, dl4, 64, 64);
  k_stem<<<dim3(4,4,8),   dim3(256), 0, stream>>>(p5, wT, b_stem, w_obj, b_obj, w_box, b_box, sc5, dl5, 32, 32);

  k_select<<<dim3(24), dim3(1024), 0, stream>>>(sc3, sc4, sc5, dl3, dl4, dl5, out);
}